// Round 17
// baseline (45.360 us; speedup 1.0000x reference)
//
#include <hip/hip_runtime.h>
#include <hip/hip_bf16.h>

// CrossSigmoidFocalLoss — R15/R16 PROBE ROUND: cfs_main launched TWICE (idempotent,
// identical partials written both times -> output bitwise identical) to measure
// main's true duration from the total: main+gap = dur - 26.39us (R14 baseline).
// The top-5 counter table is flooded by 48us harness fills, so cfs_main's
// duration is otherwise unobservable.
//
// Math per element (p = sigmoid(x)):
//   c==t: 0.25 * sigmoid(-x)^2 * softplus(-x)
//   c!=t: 0.75 * sigmoid(x)^2  * softplus(x)   [* schema bit if t==C]
// One exp/rcp/log per element; softplus(-x) = softplus(x) - x.
// weight < 2^16 so schema bits for c>=16 are 0 (c0>=32 shift guarded).
//
// Ledger: R8 __threadfence/block=+66us; R9 same-addr atomics/nt=+14.6us;
// R11 staging neutral; R12 occupancy neutral; R14 VALU-cut neutral.
// grid.sync() = 2x __threadfence per block -> cooperative fusion is DOA.

#define NCLS 80
#define C4   (NCLS / 4)              // 20 float4 per row
#define NBLOCKS 2560                 // multiple of 5 -> STRIDE % 20 == 0
#define NTHREADS 256
#define KIT 8
#define STRIDE (NBLOCKS * NTHREADS)  // 655,360 threads
#define ROWSTEP (STRIDE / C4)        // 32,768 rows per k-step

typedef float f32x4 __attribute__((ext_vector_type(4)));

__device__ __forceinline__ float quad_term(f32x4 x4, int t, float w, int c0) {
    const int   wi  = (int)w;
    const bool  neg = (t == NCLS);
    const float qn  = (w > 0.0f) ? 0.75f : 0.0f;
    const float qp  = (w > 0.0f) ? 0.25f : 0.0f;
    const int   wsh   = (c0 < 32) ? (wi >> c0) : 0;   // guard shift >= 32 (UB)
    const int   maskA = neg ? (wsh & 15) : 15;        // neg rows: schema bits; pos: all
    float acc = 0.0f;
    #pragma unroll
    for (int j = 0; j < 4; ++j) {
        const float x   = x4[j];
        const float e   = __expf(-fabsf(x));            // v_exp path
        const float d   = 1.0f + e;
        const float r   = __builtin_amdgcn_rcpf(d);     // v_rcp
        const float sB  = e * r;
        const bool  f   = (x >= 0.0f);
        const float s   = f ? r : sB;                   // sigmoid(x)
        const float s1  = f ? sB : r;                   // sigmoid(-x)
        const float lg  = __log2f(d);                   // v_log
        const float sp  = __builtin_fmaf(lg, 0.69314718055994531f, fmaxf(x, 0.0f));
        const float sp1 = sp - x;                       // softplus(-x)
        const float g   = (s * s) * sp;
        const float g1  = (s1 * s1) * sp1;
        const float cN  = ((maskA >> j) & 1) ? qn : 0.0f;
        const bool  ist = ((c0 + j) == t);              // never true on neg rows
        acc += ist ? (qp * g1) : (cN * g);
    }
    return acc;
}

template<int KITERS>
__global__ void __launch_bounds__(NTHREADS)
cfs_main(const float* __restrict__ pred,
         const int*   __restrict__ targets,
         const float* __restrict__ weight,
         float* __restrict__ partials,
         int total4) {
    const int tid = blockIdx.x * NTHREADS + threadIdx.x;

    float acc = 0.0f;
    if constexpr (KITERS > 0) {
        const int n0 = tid / C4;                  // one magic-divide, hoisted
        const int c0 = (tid - n0 * C4) * 4;       // constant across k
        #pragma unroll
        for (int k = 0; k < KITERS; ++k) {
            const int i = tid + k * STRIDE;
            const int n = n0 + k * ROWSTEP;       // 1 add per k
            const f32x4 x4 = reinterpret_cast<const f32x4*>(pred)[i];
            acc += quad_term(x4, targets[n], weight[n], c0);
        }
    } else {
        for (int i = tid; i < total4; i += STRIDE) {
            const int n  = i / C4;
            const int c0 = (i - n * C4) * 4;
            const f32x4 x4 = reinterpret_cast<const f32x4*>(pred)[i];
            acc += quad_term(x4, targets[n], weight[n], c0);
        }
    }

    // wave (64-lane) reduction
    #pragma unroll
    for (int off = 32; off > 0; off >>= 1)
        acc += __shfl_down(acc, off, 64);

    __shared__ float smem[NTHREADS / 64];
    const int lane = threadIdx.x & 63;
    const int wid  = threadIdx.x >> 6;
    if (lane == 0) smem[wid] = acc;
    __syncthreads();
    if (threadIdx.x == 0)
        partials[blockIdx.x] = smem[0] + smem[1] + smem[2] + smem[3];
}

__global__ void __launch_bounds__(NTHREADS)
cfs_reduce(const float* __restrict__ partials, float* __restrict__ out,
           int nparts4, float scale) {
    // nparts4 float4 elements; fixed-order -> deterministic
    float acc = 0.0f;
    for (int i = threadIdx.x; i < nparts4; i += NTHREADS) {
        const f32x4 p4 = reinterpret_cast<const f32x4*>(partials)[i];
        acc += (p4[0] + p4[1]) + (p4[2] + p4[3]);
    }
    #pragma unroll
    for (int off = 32; off > 0; off >>= 1)
        acc += __shfl_down(acc, off, 64);

    __shared__ float smem[NTHREADS / 64];
    const int lane = threadIdx.x & 63;
    const int wid  = threadIdx.x >> 6;
    if (lane == 0) smem[wid] = acc;
    __syncthreads();
    if (threadIdx.x == 0)
        out[0] = (smem[0] + smem[1] + smem[2] + smem[3]) * scale;
}

extern "C" void kernel_launch(void* const* d_in, const int* in_sizes, int n_in,
                              void* d_out, int out_size, void* d_ws, size_t ws_size,
                              hipStream_t stream) {
    const float* pred     = (const float*)d_in[0];
    const int*   targets  = (const int*)  d_in[1];
    const float* weight   = (const float*)d_in[2];
    float*       out      = (float*)d_out;
    float*       partials = (float*)d_ws;   // NBLOCKS floats of scratch

    const int n_rows = in_sizes[1];          // 262144
    const int total4 = n_rows * C4;          // 5,242,880
    const float inv_total = 1.0f / (float)(n_rows * NCLS);

    if (total4 == KIT * STRIDE) {
        // PROBE: two identical launches (idempotent). main+gap = dur - 26.39us.
        cfs_main<KIT><<<NBLOCKS, NTHREADS, 0, stream>>>(pred, targets, weight, partials, total4);
        cfs_main<KIT><<<NBLOCKS, NTHREADS, 0, stream>>>(pred, targets, weight, partials, total4);
    } else {
        cfs_main<0><<<NBLOCKS, NTHREADS, 0, stream>>>(pred, targets, weight, partials, total4);
    }
    cfs_reduce<<<1, NTHREADS, 0, stream>>>(partials, out, NBLOCKS / 4, inv_total);
}

// Round 18
// 25.599 us; speedup vs baseline: 1.7720x; 1.7720x over previous
//
#include <hip/hip_runtime.h>
#include <hip/hip_bf16.h>

// CrossSigmoidFocalLoss: mean over (N,C) of focal_w * bce * row_w * cross_mask
// Per element (p = sigmoid(x)):
//   c==t: 0.25 * sigmoid(-x)^2 * softplus(-x)
//   c!=t: 0.75 * sigmoid(x)^2  * softplus(x)   [* schema bit if t==C]
// One exp/rcp/log per element; softplus(-x) = softplus(x) - x.
// weight < 2^16 so schema bits for c>=16 are 0 (c0>=32 shift guarded).
//
// Ledger: R8 __threadfence/block=+66us. R9 same-addr arrival atomics=+14.6us.
// R11 staging neutral. R12 occupancy neutral. R14 VALU-cut neutral.
// R17 probe: main+gap=18.97us (L3-warm!) -> main ~17-19us internal floor;
// reduce-node path ~5.5-7.4us, dominated by the 1-block reduce's 10 serial
// dependent load rounds (~600-900ns each).
// THIS ROUND (single variable): specialized reduce -- all 640 f32x4 loads
// issue in ONE latency epoch (static [t],[t+256],(t<128)[t+512] split).

#define NCLS 80
#define C4   (NCLS / 4)              // 20 float4 per row
#define NBLOCKS 2560                 // multiple of 5 -> STRIDE % 20 == 0
#define NTHREADS 256
#define KIT 8
#define STRIDE (NBLOCKS * NTHREADS)  // 655,360 threads
#define ROWSTEP (STRIDE / C4)        // 32,768 rows per k-step

typedef float f32x4 __attribute__((ext_vector_type(4)));

__device__ __forceinline__ float quad_term(f32x4 x4, int t, float w, int c0) {
    const int   wi  = (int)w;
    const bool  neg = (t == NCLS);
    const float qn  = (w > 0.0f) ? 0.75f : 0.0f;
    const float qp  = (w > 0.0f) ? 0.25f : 0.0f;
    const int   wsh   = (c0 < 32) ? (wi >> c0) : 0;   // guard shift >= 32 (UB)
    const int   maskA = neg ? (wsh & 15) : 15;        // neg rows: schema bits; pos: all
    float acc = 0.0f;
    #pragma unroll
    for (int j = 0; j < 4; ++j) {
        const float x   = x4[j];
        const float e   = __expf(-fabsf(x));            // v_exp path
        const float d   = 1.0f + e;
        const float r   = __builtin_amdgcn_rcpf(d);     // v_rcp
        const float sB  = e * r;
        const bool  f   = (x >= 0.0f);
        const float s   = f ? r : sB;                   // sigmoid(x)
        const float s1  = f ? sB : r;                   // sigmoid(-x)
        const float lg  = __log2f(d);                   // v_log
        const float sp  = __builtin_fmaf(lg, 0.69314718055994531f, fmaxf(x, 0.0f));
        const float sp1 = sp - x;                       // softplus(-x)
        const float g   = (s * s) * sp;
        const float g1  = (s1 * s1) * sp1;
        const float cN  = ((maskA >> j) & 1) ? qn : 0.0f;
        const bool  ist = ((c0 + j) == t);              // never true on neg rows
        acc += ist ? (qp * g1) : (cN * g);
    }
    return acc;
}

template<int KITERS>
__global__ void __launch_bounds__(NTHREADS)
cfs_main(const float* __restrict__ pred,
         const int*   __restrict__ targets,
         const float* __restrict__ weight,
         float* __restrict__ partials,
         int total4) {
    const int tid = blockIdx.x * NTHREADS + threadIdx.x;

    float acc = 0.0f;
    if constexpr (KITERS > 0) {
        const int n0 = tid / C4;                  // one magic-divide, hoisted
        const int c0 = (tid - n0 * C4) * 4;       // constant across k
        #pragma unroll
        for (int k = 0; k < KITERS; ++k) {
            const int i = tid + k * STRIDE;
            const int n = n0 + k * ROWSTEP;       // 1 add per k
            const f32x4 x4 = reinterpret_cast<const f32x4*>(pred)[i];
            acc += quad_term(x4, targets[n], weight[n], c0);
        }
    } else {
        for (int i = tid; i < total4; i += STRIDE) {
            const int n  = i / C4;
            const int c0 = (i - n * C4) * 4;
            const f32x4 x4 = reinterpret_cast<const f32x4*>(pred)[i];
            acc += quad_term(x4, targets[n], weight[n], c0);
        }
    }

    // wave (64-lane) reduction
    #pragma unroll
    for (int off = 32; off > 0; off >>= 1)
        acc += __shfl_down(acc, off, 64);

    __shared__ float smem[NTHREADS / 64];
    const int lane = threadIdx.x & 63;
    const int wid  = threadIdx.x >> 6;
    if (lane == 0) smem[wid] = acc;
    __syncthreads();
    if (threadIdx.x == 0)
        partials[blockIdx.x] = smem[0] + smem[1] + smem[2] + smem[3];
}

// Specialized reduce for NBLOCKS==2560 (= 640 f32x4): every load issues before
// any use -> ONE latency epoch instead of 10 serial rounds. Fixed-order sum ->
// bitwise deterministic.
__global__ void __launch_bounds__(NTHREADS)
cfs_reduce2560(const float* __restrict__ partials, float* __restrict__ out,
               float scale) {
    const int t = threadIdx.x;
    const f32x4* p4 = reinterpret_cast<const f32x4*>(partials);
    const f32x4 a = p4[t];
    const f32x4 b = p4[t + 256];
    f32x4 c = {0.0f, 0.0f, 0.0f, 0.0f};
    if (t < 128) c = p4[t + 512];
    float acc = ((a[0] + a[1]) + (a[2] + a[3]))
              + ((b[0] + b[1]) + (b[2] + b[3]))
              + ((c[0] + c[1]) + (c[2] + c[3]));

    #pragma unroll
    for (int off = 32; off > 0; off >>= 1)
        acc += __shfl_down(acc, off, 64);

    __shared__ float smem[NTHREADS / 64];
    const int lane = t & 63;
    const int wid  = t >> 6;
    if (lane == 0) smem[wid] = acc;
    __syncthreads();
    if (t == 0)
        out[0] = (smem[0] + smem[1] + smem[2] + smem[3]) * scale;
}

__global__ void __launch_bounds__(NTHREADS)
cfs_reduce_gen(const float* __restrict__ partials, float* __restrict__ out,
               int nparts, float scale) {
    float acc = 0.0f;
    for (int i = threadIdx.x; i < nparts; i += NTHREADS)
        acc += partials[i];
    #pragma unroll
    for (int off = 32; off > 0; off >>= 1)
        acc += __shfl_down(acc, off, 64);

    __shared__ float smem[NTHREADS / 64];
    const int lane = threadIdx.x & 63;
    const int wid  = threadIdx.x >> 6;
    if (lane == 0) smem[wid] = acc;
    __syncthreads();
    if (threadIdx.x == 0)
        out[0] = (smem[0] + smem[1] + smem[2] + smem[3]) * scale;
}

extern "C" void kernel_launch(void* const* d_in, const int* in_sizes, int n_in,
                              void* d_out, int out_size, void* d_ws, size_t ws_size,
                              hipStream_t stream) {
    const float* pred     = (const float*)d_in[0];
    const int*   targets  = (const int*)  d_in[1];
    const float* weight   = (const float*)d_in[2];
    float*       out      = (float*)d_out;
    float*       partials = (float*)d_ws;   // NBLOCKS floats of scratch

    const int n_rows = in_sizes[1];          // 262144
    const int total4 = n_rows * C4;          // 5,242,880
    const float inv_total = 1.0f / (float)(n_rows * NCLS);

    if (total4 == KIT * STRIDE) {
        cfs_main<KIT><<<NBLOCKS, NTHREADS, 0, stream>>>(pred, targets, weight, partials, total4);
        cfs_reduce2560<<<1, NTHREADS, 0, stream>>>(partials, out, inv_total);
    } else {
        cfs_main<0><<<NBLOCKS, NTHREADS, 0, stream>>>(pred, targets, weight, partials, total4);
        cfs_reduce_gen<<<1, NTHREADS, 0, stream>>>(partials, out, NBLOCKS, inv_total);
    }
}

// Round 19
// 24.902 us; speedup vs baseline: 1.8215x; 1.0280x over previous
//
#include <hip/hip_runtime.h>
#include <hip/hip_bf16.h>

// CrossSigmoidFocalLoss: mean over (N,C) of focal_w * bce * row_w * cross_mask
// Per element (p = sigmoid(x)):
//   c==t: 0.25 * sigmoid(-x)^2 * softplus(-x)
//   c!=t: 0.75 * sigmoid(x)^2  * softplus(x)   [* schema bit if t==C]
// One exp/rcp/log per element; softplus(-x) = softplus(x) - x.
// weight < 2^16 so schema bits for c>=16 are 0 (c0>=32 shift guarded).
//
// Ledger: R8 __threadfence/block=+66us. R9 same-addr arrival atomics=+14.6us.
// R11 staging neutral. R12 occupancy(4096blk) neutral. R14 VALU-cut neutral.
// R17 probe: main+gap ~= 19us even L3-warm. R18 one-epoch reduce: -0.8us only
// -> reduce-path is node-gap/drain (~5-6us), not load latency. Device fusion
// structurally blocked (no state-free last-arrival under no-re-poison replays;
// hipMemsetAsync is itself a kernel node).
// THIS ROUND (single variable, geometry): 2048 blocks x KIT=10 x
// __launch_bounds__(256,8) -> exactly 8192 waves = ONE resident batch
// (8 waves/SIMD x 4 SIMD x 256 CU), zero ragged tail.

#define NCLS 80
#define C4   (NCLS / 4)              // 20 float4 per row
#define NBLOCKS 2048
#define NTHREADS 256
#define KIT 10
#define STRIDE (NBLOCKS * NTHREADS)  // 524,288 threads = 8192 waves

typedef float f32x4 __attribute__((ext_vector_type(4)));

__device__ __forceinline__ float quad_term(f32x4 x4, int t, float w, int c0) {
    const int   wi  = (int)w;
    const bool  neg = (t == NCLS);
    const float qn  = (w > 0.0f) ? 0.75f : 0.0f;
    const float qp  = (w > 0.0f) ? 0.25f : 0.0f;
    const int   wsh   = (c0 < 32) ? (wi >> c0) : 0;   // guard shift >= 32 (UB)
    const int   maskA = neg ? (wsh & 15) : 15;        // neg rows: schema bits; pos: all
    float acc = 0.0f;
    #pragma unroll
    for (int j = 0; j < 4; ++j) {
        const float x   = x4[j];
        const float e   = __expf(-fabsf(x));            // v_exp path
        const float d   = 1.0f + e;
        const float r   = __builtin_amdgcn_rcpf(d);     // v_rcp
        const float sB  = e * r;
        const bool  f   = (x >= 0.0f);
        const float s   = f ? r : sB;                   // sigmoid(x)
        const float s1  = f ? sB : r;                   // sigmoid(-x)
        const float lg  = __log2f(d);                   // v_log
        const float sp  = __builtin_fmaf(lg, 0.69314718055994531f, fmaxf(x, 0.0f));
        const float sp1 = sp - x;                       // softplus(-x)
        const float g   = (s * s) * sp;
        const float g1  = (s1 * s1) * sp1;
        const float cN  = ((maskA >> j) & 1) ? qn : 0.0f;
        const bool  ist = ((c0 + j) == t);              // never true on neg rows
        acc += ist ? (qp * g1) : (cN * g);
    }
    return acc;
}

template<int KITERS>
__global__ void __launch_bounds__(NTHREADS, 8)
cfs_main(const float* __restrict__ pred,
         const int*   __restrict__ targets,
         const float* __restrict__ weight,
         float* __restrict__ partials,
         int total4) {
    const int tid = blockIdx.x * NTHREADS + threadIdx.x;

    float acc = 0.0f;
    if constexpr (KITERS > 0) {
        #pragma unroll
        for (int k = 0; k < KITERS; ++k) {
            const int i  = tid + k * STRIDE;
            const int n  = i / C4;              // magic-mul divide by 20
            const int c0 = (i - n * C4) * 4;
            const f32x4 x4 = reinterpret_cast<const f32x4*>(pred)[i];
            acc += quad_term(x4, targets[n], weight[n], c0);
        }
    } else {
        for (int i = tid; i < total4; i += STRIDE) {
            const int n  = i / C4;
            const int c0 = (i - n * C4) * 4;
            const f32x4 x4 = reinterpret_cast<const f32x4*>(pred)[i];
            acc += quad_term(x4, targets[n], weight[n], c0);
        }
    }

    // wave (64-lane) reduction
    #pragma unroll
    for (int off = 32; off > 0; off >>= 1)
        acc += __shfl_down(acc, off, 64);

    __shared__ float smem[NTHREADS / 64];
    const int lane = threadIdx.x & 63;
    const int wid  = threadIdx.x >> 6;
    if (lane == 0) smem[wid] = acc;
    __syncthreads();
    if (threadIdx.x == 0)
        partials[blockIdx.x] = smem[0] + smem[1] + smem[2] + smem[3];
}

// Specialized reduce for NBLOCKS==2048 (= 512 f32x4): both loads per thread
// issue before any use -> one latency epoch. Fixed-order -> deterministic.
__global__ void __launch_bounds__(NTHREADS)
cfs_reduce2048(const float* __restrict__ partials, float* __restrict__ out,
               float scale) {
    const int t = threadIdx.x;
    const f32x4* p4 = reinterpret_cast<const f32x4*>(partials);
    const f32x4 a = p4[t];
    const f32x4 b = p4[t + 256];
    float acc = ((a[0] + a[1]) + (a[2] + a[3]))
              + ((b[0] + b[1]) + (b[2] + b[3]));

    #pragma unroll
    for (int off = 32; off > 0; off >>= 1)
        acc += __shfl_down(acc, off, 64);

    __shared__ float smem[NTHREADS / 64];
    const int lane = t & 63;
    const int wid  = t >> 6;
    if (lane == 0) smem[wid] = acc;
    __syncthreads();
    if (t == 0)
        out[0] = (smem[0] + smem[1] + smem[2] + smem[3]) * scale;
}

__global__ void __launch_bounds__(NTHREADS)
cfs_reduce_gen(const float* __restrict__ partials, float* __restrict__ out,
               int nparts, float scale) {
    float acc = 0.0f;
    for (int i = threadIdx.x; i < nparts; i += NTHREADS)
        acc += partials[i];
    #pragma unroll
    for (int off = 32; off > 0; off >>= 1)
        acc += __shfl_down(acc, off, 64);

    __shared__ float smem[NTHREADS / 64];
    const int lane = threadIdx.x & 63;
    const int wid  = threadIdx.x >> 6;
    if (lane == 0) smem[wid] = acc;
    __syncthreads();
    if (threadIdx.x == 0)
        out[0] = (smem[0] + smem[1] + smem[2] + smem[3]) * scale;
}

extern "C" void kernel_launch(void* const* d_in, const int* in_sizes, int n_in,
                              void* d_out, int out_size, void* d_ws, size_t ws_size,
                              hipStream_t stream) {
    const float* pred     = (const float*)d_in[0];
    const int*   targets  = (const int*)  d_in[1];
    const float* weight   = (const float*)d_in[2];
    float*       out      = (float*)d_out;
    float*       partials = (float*)d_ws;   // NBLOCKS floats of scratch

    const int n_rows = in_sizes[1];          // 262144
    const int total4 = n_rows * C4;          // 5,242,880
    const float inv_total = 1.0f / (float)(n_rows * NCLS);

    if (total4 == KIT * STRIDE) {
        cfs_main<KIT><<<NBLOCKS, NTHREADS, 0, stream>>>(pred, targets, weight, partials, total4);
        cfs_reduce2048<<<1, NTHREADS, 0, stream>>>(partials, out, inv_total);
    } else {
        cfs_main<0><<<NBLOCKS, NTHREADS, 0, stream>>>(pred, targets, weight, partials, total4);
        cfs_reduce_gen<<<1, NTHREADS, 0, stream>>>(partials, out, NBLOCKS, inv_total);
    }
}